// Round 8
// baseline (398.431 us; speedup 1.0000x reference)
//
#include <hip/hip_runtime.h>

#define BN_EPS 1e-5f

typedef __attribute__((ext_vector_type(8))) __bf16 bf16x8;
typedef __attribute__((ext_vector_type(4))) float f32x4;

__device__ __forceinline__ unsigned short f2bf(float f) {
    unsigned int u = __float_as_uint(f);
    u = (u + 0x7fffu + ((u >> 16) & 1u)) >> 16;
    return (unsigned short)u;
}
__device__ __forceinline__ float bfLo(unsigned int w) { return __uint_as_float(w << 16); }
__device__ __forceinline__ float bfHi(unsigned int w) { return __uint_as_float(w & 0xffff0000u); }

__device__ __forceinline__ void acc8_raw(float* acc, uint4 v) {
    acc[0] += bfLo(v.x); acc[1] += bfHi(v.x);
    acc[2] += bfLo(v.y); acc[3] += bfHi(v.y);
    acc[4] += bfLo(v.z); acc[5] += bfHi(v.z);
    acc[6] += bfLo(v.w); acc[7] += bfHi(v.w);
}
__device__ __forceinline__ void acc8_bn(float* acc, uint4 v, const float* a, const float* c) {
    acc[0] += fmaxf(fmaf(bfLo(v.x), a[0], c[0]), 0.f);
    acc[1] += fmaxf(fmaf(bfHi(v.x), a[1], c[1]), 0.f);
    acc[2] += fmaxf(fmaf(bfLo(v.y), a[2], c[2]), 0.f);
    acc[3] += fmaxf(fmaf(bfHi(v.y), a[3], c[3]), 0.f);
    acc[4] += fmaxf(fmaf(bfLo(v.z), a[4], c[4]), 0.f);
    acc[5] += fmaxf(fmaf(bfHi(v.z), a[5], c[5]), 0.f);
    acc[6] += fmaxf(fmaf(bfLo(v.w), a[6], c[6]), 0.f);
    acc[7] += fmaxf(fmaf(bfHi(v.w), a[7], c[7]), 0.f);
}

// ============ one-time prep: x -> bf16 AND swizzle all 3 weights ============
// Wsw[((ct*4+q)*64 + l)*8 + j] = bf16( W[q*32 + (l>>4)*8 + j][ct*16 + (l&15)] )
__global__ void convert_and_prep(const float* __restrict__ x, unsigned short* __restrict__ hb,
                                 int total4,
                                 const float* __restrict__ W1, const float* __restrict__ W2,
                                 const float* __restrict__ W3,
                                 unsigned short* __restrict__ w1s, unsigned short* __restrict__ w2s,
                                 unsigned short* __restrict__ w3s) {
    int tid0 = blockIdx.x * blockDim.x + threadIdx.x;
    if (tid0 < 40960) {
        int idx = tid0;
        const float* W; unsigned short* O; int NOUT;
        if (idx < 16384)      { W = W1; O = w1s; NOUT = 128; }
        else if (idx < 32768) { W = W2; O = w2s; NOUT = 128; idx -= 16384; }
        else                  { W = W3; O = w3s; NOUT = 64;  idx -= 32768; }
        int j = idx & 7;
        int l = (idx >> 3) & 63;
        int q = (idx >> 9) & 3;
        int ct = idx >> 11;
        int k = q * 32 + ((l >> 4) & 3) * 8 + j;
        int c = ct * 16 + (l & 15);
        O[idx] = f2bf(W[(size_t)k * NOUT + c]);
    }
    int stride = gridDim.x * blockDim.x;
    for (int i = tid0; i < total4; i += stride) {
        float4 v = reinterpret_cast<const float4*>(x)[i];
        ushort4 o;
        o.x = f2bf(v.x); o.y = f2bf(v.y); o.z = f2bf(v.z); o.w = f2bf(v.w);
        reinterpret_cast<ushort4*>(hb)[i] = o;
    }
}

// ================= CSR =================

__global__ void hist_kernel(const int* __restrict__ dst, int* __restrict__ deg, int E) {
    int e = blockIdx.x * blockDim.x + threadIdx.x;
    if (e < E) atomicAdd(&deg[dst[e]], 1);
}

// one-kernel scan: per-chunk scan + grid barrier (co-resident: nChunks<=256) + top-scan + finalize
__global__ void build_rowptr(const int* __restrict__ deg, int* __restrict__ rowptr,
                             int* __restrict__ pos, int* __restrict__ bsum,
                             int* __restrict__ arrive, int N, int E, int nChunks) {
    __shared__ int s[256];
    const int tid = threadIdx.x;
    const int b = blockIdx.x;
    const int i = b * 256 + tid;
    const int v = (i < N) ? deg[i] : 0;
    s[tid] = v;
    __syncthreads();
#pragma unroll
    for (int off = 1; off < 256; off <<= 1) {
        int t = (tid >= off) ? s[tid - off] : 0;
        __syncthreads();
        s[tid] += t;
        __syncthreads();
    }
    const int incl = s[tid];
    if (tid == 255) bsum[b] = incl;
    __threadfence();
    __syncthreads();
    if (tid == 0) {
        __hip_atomic_fetch_add(arrive, 1, __ATOMIC_ACQ_REL, __HIP_MEMORY_SCOPE_AGENT);
        while (__hip_atomic_load(arrive, __ATOMIC_ACQUIRE, __HIP_MEMORY_SCOPE_AGENT) < nChunks) {}
    }
    __syncthreads();
    // sum of chunk totals before b
    int val = (tid < b && tid < nChunks)
                  ? __hip_atomic_load(&bsum[tid], __ATOMIC_RELAXED, __HIP_MEMORY_SCOPE_AGENT)
                  : 0;
    __syncthreads();
    s[tid] = val;
    __syncthreads();
#pragma unroll
    for (int off = 128; off > 0; off >>= 1) {
        if (tid < off) s[tid] += s[tid + off];
        __syncthreads();
    }
    const int base = s[0];
    if (i < N) {
        int r = incl - v + base;
        rowptr[i] = r;
        pos[i] = r;
    }
    if (b == 0 && tid == 0) rowptr[N] = E;
}

__global__ void fill_kernel(const int* __restrict__ src, const int* __restrict__ dst,
                            int* __restrict__ pos, int* __restrict__ col, int E) {
    int e = blockIdx.x * blockDim.x + threadIdx.x;
    if (e < E) {
        int slot = atomicAdd(&pos[dst[e]], 1);
        col[slot] = src[e];
    }
}

// ========== fused gather + MFMA GEMM(NOUT=128) + bias + stats + last-block BN coefs ==========
// HAS_BN: source rows transformed by relu(a*x+c) on the fly (coefs precomputed, 128 each).
template <bool HAS_BN>
__global__ __launch_bounds__(256) void fused_g_gemm128(
    const unsigned short* __restrict__ h, const int* __restrict__ rowptr,
    const int* __restrict__ col, const float* __restrict__ aC, const float* __restrict__ cC,
    const unsigned short* __restrict__ Wsw, const float* __restrict__ bias,
    unsigned short* __restrict__ outb, float* __restrict__ sumsPad, float* __restrict__ sqsPad,
    int* __restrict__ doneCnt, const float* __restrict__ gOwn, const float* __restrict__ beOwn,
    float* __restrict__ aOut, float* __restrict__ cOut, int N, float invN) {
    __shared__ float red[2][4][128];
    __shared__ int lastFlag;
    const int lane = threadIdx.x & 63;
    const int w = threadIdx.x >> 6;
    const int r0 = blockIdx.x * 64 + w * 16;
    int row = r0 + (lane & 15);
    if (row >= N) row = N - 1;
    const int kb = lane >> 4;
    const int cbase = kb * 8;  // within each q-chunk

    float a4[4][8], c4[4][8];
    if (HAS_BN) {
#pragma unroll
        for (int q = 0; q < 4; ++q) {
            const float4* ap = reinterpret_cast<const float4*>(aC + q * 32 + cbase);
            const float4* cp = reinterpret_cast<const float4*>(cC + q * 32 + cbase);
            float4 A0 = ap[0], A1 = ap[1], C0 = cp[0], C1 = cp[1];
            a4[q][0] = A0.x; a4[q][1] = A0.y; a4[q][2] = A0.z; a4[q][3] = A0.w;
            a4[q][4] = A1.x; a4[q][5] = A1.y; a4[q][6] = A1.z; a4[q][7] = A1.w;
            c4[q][0] = C0.x; c4[q][1] = C0.y; c4[q][2] = C0.z; c4[q][3] = C0.w;
            c4[q][4] = C1.x; c4[q][5] = C1.y; c4[q][6] = C1.z; c4[q][7] = C1.w;
        }
    }

    // gather-accumulate this lane's A-fragment columns: acc[q][j] = sum over {self, neighbors}
    float acc[4][8];
    {
        const unsigned short* sp = h + (size_t)row * 128 + cbase;
#pragma unroll
        for (int q = 0; q < 4; ++q) {
            uint4 v = *reinterpret_cast<const uint4*>(sp + q * 32);
#pragma unroll
            for (int j = 0; j < 8; ++j) acc[q][j] = 0.f;
            if (HAS_BN) acc8_bn(acc[q], v, a4[q], c4[q]);
            else        acc8_raw(acc[q], v);
        }
    }
    const int beg = rowptr[row], end = rowptr[row + 1];
    int e = beg;
    for (; e + 1 < end; e += 2) {
        int s0 = col[e], s1 = col[e + 1];
        const unsigned short* p0 = h + (size_t)s0 * 128 + cbase;
        const unsigned short* p1 = h + (size_t)s1 * 128 + cbase;
        uint4 v0[4], v1[4];
#pragma unroll
        for (int q = 0; q < 4; ++q) v0[q] = *reinterpret_cast<const uint4*>(p0 + q * 32);
#pragma unroll
        for (int q = 0; q < 4; ++q) v1[q] = *reinterpret_cast<const uint4*>(p1 + q * 32);
#pragma unroll
        for (int q = 0; q < 4; ++q) {
            if (HAS_BN) { acc8_bn(acc[q], v0[q], a4[q], c4[q]); acc8_bn(acc[q], v1[q], a4[q], c4[q]); }
            else        { acc8_raw(acc[q], v0[q]); acc8_raw(acc[q], v1[q]); }
        }
    }
    if (e < end) {
        const unsigned short* p0 = h + (size_t)col[e] * 128 + cbase;
#pragma unroll
        for (int q = 0; q < 4; ++q) {
            uint4 v = *reinterpret_cast<const uint4*>(p0 + q * 32);
            if (HAS_BN) acc8_bn(acc[q], v, a4[q], c4[q]);
            else        acc8_raw(acc[q], v);
        }
    }

    // pack to bf16 fragments
    bf16x8 a[4];
#pragma unroll
    for (int q = 0; q < 4; ++q) {
        uint4 hp;
        hp.x = (unsigned int)f2bf(acc[q][0]) | ((unsigned int)f2bf(acc[q][1]) << 16);
        hp.y = (unsigned int)f2bf(acc[q][2]) | ((unsigned int)f2bf(acc[q][3]) << 16);
        hp.z = (unsigned int)f2bf(acc[q][4]) | ((unsigned int)f2bf(acc[q][5]) << 16);
        hp.w = (unsigned int)f2bf(acc[q][6]) | ((unsigned int)f2bf(acc[q][7]) << 16);
        a[q] = *reinterpret_cast<bf16x8*>(&hp);
    }

    f32x4 mac[8];
#pragma unroll
    for (int ct = 0; ct < 8; ++ct) mac[ct] = (f32x4){0.f, 0.f, 0.f, 0.f};
    const bf16x8* wp = reinterpret_cast<const bf16x8*>(Wsw) + lane;
#pragma unroll
    for (int ct = 0; ct < 8; ++ct)
#pragma unroll
        for (int q = 0; q < 4; ++q)
            mac[ct] = __builtin_amdgcn_mfma_f32_16x16x32_bf16(a[q], wp[(ct * 4 + q) * 64],
                                                              mac[ct], 0, 0, 0);

    const int crow0 = r0 + (lane >> 4) * 4;
    const int ccol = lane & 15;
#pragma unroll
    for (int ct = 0; ct < 8; ++ct) {
        int c = ct * 16 + ccol;
        float bv = bias[c];
        float s = 0.f, qq = 0.f;
#pragma unroll
        for (int j = 0; j < 4; ++j) {
            int r = crow0 + j;
            if (r < N) {
                float o = mac[ct][j] + bv;
                outb[(size_t)r * 128 + c] = f2bf(o);
                s += o; qq += o * o;
            }
        }
        s += __shfl_xor(s, 16); s += __shfl_xor(s, 32);
        qq += __shfl_xor(qq, 16); qq += __shfl_xor(qq, 32);
        if (lane < 16) { red[0][w][c] = s; red[1][w][c] = qq; }
    }
    __syncthreads();
    int tid = threadIdx.x;
    if (tid < 128) {
        float S = red[0][0][tid] + red[0][1][tid] + red[0][2][tid] + red[0][3][tid];
        atomicAdd(&sumsPad[tid * 16], S);
    } else {
        int c = tid - 128;
        float Q = red[1][0][c] + red[1][1][c] + red[1][2][c] + red[1][3][c];
        atomicAdd(&sqsPad[c * 16], Q);
    }
    // last block folds stats into next-stage BN coefs
    __threadfence();
    if (tid == 0) lastFlag = (atomicAdd(doneCnt, 1) == (int)gridDim.x - 1);
    __syncthreads();
    if (lastFlag && tid < 128) {
        float S = __hip_atomic_load(&sumsPad[tid * 16], __ATOMIC_RELAXED, __HIP_MEMORY_SCOPE_AGENT);
        float Q = __hip_atomic_load(&sqsPad[tid * 16], __ATOMIC_RELAXED, __HIP_MEMORY_SCOPE_AGENT);
        float m = S * invN;
        float var = Q * invN - m * m;
        float ai = gOwn[tid] * rsqrtf(var + BN_EPS);
        aOut[tid] = ai;
        cOut[tid] = beOwn[tid] - m * ai;
    }
}

// ========== MFMA GEMM (NOUT=64), BN2+ReLU on A via precomputed coefs; M = relu(bn(raw))@W3 ==========
__global__ __launch_bounds__(256) void gemm64_bn(const unsigned short* __restrict__ raw,
                                                 const float* __restrict__ aC,
                                                 const float* __restrict__ cC,
                                                 const unsigned short* __restrict__ Wsw,
                                                 unsigned short* __restrict__ M, int N) {
    const int lane = threadIdx.x & 63;
    const int w = threadIdx.x >> 6;
    const int r0 = blockIdx.x * 64 + w * 16;
    int arow = r0 + (lane & 15);
    if (arow >= N) arow = N - 1;
    const int kb = lane >> 4;
    const unsigned short* ap = raw + (size_t)arow * 128 + kb * 8;

    bf16x8 a[4];
#pragma unroll
    for (int q = 0; q < 4; ++q) {
        uint4 rv = *reinterpret_cast<const uint4*>(ap + q * 32);
        const float4* af = reinterpret_cast<const float4*>(aC + q * 32 + kb * 8);
        const float4* cf = reinterpret_cast<const float4*>(cC + q * 32 + kb * 8);
        float4 A0 = af[0], A1 = af[1], C0 = cf[0], C1 = cf[1];
        uint4 hp;
        hp.x = (unsigned int)f2bf(fmaxf(fmaf(bfLo(rv.x), A0.x, C0.x), 0.f)) |
               ((unsigned int)f2bf(fmaxf(fmaf(bfHi(rv.x), A0.y, C0.y), 0.f)) << 16);
        hp.y = (unsigned int)f2bf(fmaxf(fmaf(bfLo(rv.y), A0.z, C0.z), 0.f)) |
               ((unsigned int)f2bf(fmaxf(fmaf(bfHi(rv.y), A0.w, C0.w), 0.f)) << 16);
        hp.z = (unsigned int)f2bf(fmaxf(fmaf(bfLo(rv.z), A1.x, C1.x), 0.f)) |
               ((unsigned int)f2bf(fmaxf(fmaf(bfHi(rv.z), A1.y, C1.y), 0.f)) << 16);
        hp.w = (unsigned int)f2bf(fmaxf(fmaf(bfLo(rv.w), A1.z, C1.z), 0.f)) |
               ((unsigned int)f2bf(fmaxf(fmaf(bfHi(rv.w), A1.w, C1.w), 0.f)) << 16);
        a[q] = *reinterpret_cast<bf16x8*>(&hp);
    }

    f32x4 acc[4];
#pragma unroll
    for (int ct = 0; ct < 4; ++ct) acc[ct] = (f32x4){0.f, 0.f, 0.f, 0.f};
    const bf16x8* wp = reinterpret_cast<const bf16x8*>(Wsw) + lane;
#pragma unroll
    for (int ct = 0; ct < 4; ++ct)
#pragma unroll
        for (int q = 0; q < 4; ++q)
            acc[ct] = __builtin_amdgcn_mfma_f32_16x16x32_bf16(a[q], wp[(ct * 4 + q) * 64],
                                                              acc[ct], 0, 0, 0);

    const int crow0 = r0 + (lane >> 4) * 4;
    const int ccol = lane & 15;
#pragma unroll
    for (int ct = 0; ct < 4; ++ct) {
        int c = ct * 16 + ccol;
#pragma unroll
        for (int j = 0; j < 4; ++j) {
            int r = crow0 + j;
            if (r < N) M[(size_t)r * 64 + c] = f2bf(acc[ct][j]);
        }
    }
}

// ========== layer-3 gather on M (64-wide) + bias + log_softmax; 8 lanes/node ==========
__global__ void gather64_lsm(const unsigned short* __restrict__ M,
                             const int* __restrict__ rowptr, const int* __restrict__ col,
                             const float* __restrict__ bias, float* __restrict__ out, int N) {
    int t = blockIdx.x * blockDim.x + threadIdx.x;
    int node = t >> 3;
    if (node >= N) return;
    int part = (t & 7) * 8;
    const unsigned short* mp = M + part;
    const int beg = rowptr[node], end = rowptr[node + 1];

    float acc[8];
    {
        uint4 sv = *reinterpret_cast<const uint4*>(mp + (size_t)node * 64);
        acc[0] = bfLo(sv.x); acc[1] = bfHi(sv.x);
        acc[2] = bfLo(sv.y); acc[3] = bfHi(sv.y);
        acc[4] = bfLo(sv.z); acc[5] = bfHi(sv.z);
        acc[6] = bfLo(sv.w); acc[7] = bfHi(sv.w);
    }
    int e = beg;
    for (; e + 3 < end; e += 4) {
        int s0 = col[e], s1 = col[e + 1], s2 = col[e + 2], s3 = col[e + 3];
        uint4 v0 = *reinterpret_cast<const uint4*>(mp + (size_t)s0 * 64);
        uint4 v1 = *reinterpret_cast<const uint4*>(mp + (size_t)s1 * 64);
        uint4 v2 = *reinterpret_cast<const uint4*>(mp + (size_t)s2 * 64);
        uint4 v3 = *reinterpret_cast<const uint4*>(mp + (size_t)s3 * 64);
        acc8_raw(acc, v0); acc8_raw(acc, v1); acc8_raw(acc, v2); acc8_raw(acc, v3);
    }
    for (; e < end; ++e)
        acc8_raw(acc, *reinterpret_cast<const uint4*>(mp + (size_t)col[e] * 64));

#pragma unroll
    for (int k = 0; k < 8; ++k) acc[k] += bias[part + k];

    float m = acc[0];
#pragma unroll
    for (int k = 1; k < 8; ++k) m = fmaxf(m, acc[k]);
#pragma unroll
    for (int off = 1; off < 8; off <<= 1) m = fmaxf(m, __shfl_xor(m, off));
    float s = 0.f;
#pragma unroll
    for (int k = 0; k < 8; ++k) s += __expf(acc[k] - m);
#pragma unroll
    for (int off = 1; off < 8; off <<= 1) s += __shfl_xor(s, off);
    float ml = m + __logf(s);

    float4 o0, o1;
    o0.x = acc[0] - ml; o0.y = acc[1] - ml; o0.z = acc[2] - ml; o0.w = acc[3] - ml;
    o1.x = acc[4] - ml; o1.y = acc[5] - ml; o1.z = acc[6] - ml; o1.w = acc[7] - ml;
    float* op = out + (size_t)node * 64 + part;
    *reinterpret_cast<float4*>(op) = o0;
    *reinterpret_cast<float4*>(op + 4) = o1;
}

extern "C" void kernel_launch(void* const* d_in, const int* in_sizes, int n_in,
                              void* d_out, int out_size, void* d_ws, size_t ws_size,
                              hipStream_t stream) {
    const float* x   = (const float*)d_in[0];
    const int*   ei  = (const int*)d_in[1];
    const float* W1  = (const float*)d_in[2];
    const float* b1  = (const float*)d_in[3];
    const float* g1  = (const float*)d_in[4];
    const float* be1 = (const float*)d_in[5];
    const float* W2  = (const float*)d_in[6];
    const float* b2  = (const float*)d_in[7];
    const float* g2  = (const float*)d_in[8];
    const float* be2 = (const float*)d_in[9];
    const float* W3  = (const float*)d_in[10];
    const float* b3  = (const float*)d_in[11];

    const int N = in_sizes[0] / 128;
    const int E = in_sizes[1] / 2;
    const int* src = ei;
    const int* dst = ei + E;

    // ---- workspace carve-up; [statsPad|coefs|cnts|deg] is one memset region ----
    float* statsPad = (float*)d_ws;                 // 4 x 2048 (stride-16 cols)
    float* sums1 = statsPad;
    float* sqs1  = statsPad + 2048;
    float* sums2 = statsPad + 4096;
    float* sqs2  = statsPad + 6144;
    float* a1    = statsPad + 8192;                 // 128
    float* c1    = a1 + 128;
    float* a2    = c1 + 128;
    float* c2    = a2 + 128;
    int* cnts   = (int*)(c2 + 128);                 // 64: [done1, done2, arrive, ...]
    int* deg    = cnts + 64;                        // N
    int* pos    = deg + N;                          // N
    int* rowptr = pos + N;                          // N+1
    int* bsum   = rowptr + N + 1;                   // 256
    int* colidx = bsum + 256;                       // E
    unsigned short* hb   = (unsigned short*)(colidx + E);   // N*128 bf16 (x)
    unsigned short* raw1 = hb + (size_t)N * 128;            // N*128 bf16 (layer1 gemm out)
    unsigned short* raw2 = raw1 + (size_t)N * 128;          // N*128 bf16 (layer2 gemm out)
    unsigned short* m3   = raw2 + (size_t)N * 128;          // N*64 bf16 (layer3 pre-agg)
    unsigned short* w1s  = m3 + (size_t)N * 64;             // 16384
    unsigned short* w2s  = w1s + 16384;                     // 16384
    unsigned short* w3s  = w2s + 16384;                     // 8192

    const int nChunks = (N + 255) / 256;
    const int eBlocks = (E + 255) / 256;
    const int gemmBlocks = (N + 63) / 64;
    const int gather64Blocks = (N * 8 + 255) / 256;
    const int total4 = N * 128 / 4;
    const float invN = 1.0f / N;

    const size_t zeroBytes = (8192 + 512) * sizeof(float) + (64 + (size_t)N) * sizeof(int);
    hipMemsetAsync(statsPad, 0, zeroBytes, stream);

    // ---- prep + CSR ----
    convert_and_prep<<<2048, 256, 0, stream>>>(x, hb, total4, W1, W2, W3, w1s, w2s, w3s);
    hist_kernel<<<eBlocks, 256, 0, stream>>>(dst, deg, E);
    build_rowptr<<<nChunks, 256, 0, stream>>>(deg, rowptr, pos, bsum, cnts + 2, N, E, nChunks);
    fill_kernel<<<eBlocks, 256, 0, stream>>>(src, dst, pos, colidx, E);

    // ---- layer 1: fused gather + GEMM + stats (+ last-block BN1 coefs) ----
    fused_g_gemm128<false><<<gemmBlocks, 256, 0, stream>>>(
        hb, rowptr, colidx, nullptr, nullptr, w1s, b1, raw1, sums1, sqs1,
        cnts + 0, g1, be1, a1, c1, N, invN);

    // ---- layer 2: fused BN1+ReLU gather + GEMM + stats (+ BN2 coefs) ----
    fused_g_gemm128<true><<<gemmBlocks, 256, 0, stream>>>(
        raw1, rowptr, colidx, a1, c1, w2s, b2, raw2, sums2, sqs2,
        cnts + 1, g2, be2, a2, c2, N, invN);

    // ---- layer 3: GEMM (BN2+ReLU inline) then 64-wide gather + bias + log_softmax ----
    gemm64_bn<<<gemmBlocks, 256, 0, stream>>>(raw2, a2, c2, w3s, m3, N);
    gather64_lsm<<<gather64Blocks, 256, 0, stream>>>(m3, rowptr, colidx, b3, (float*)d_out, N);
}

// Round 9
// 282.318 us; speedup vs baseline: 1.4113x; 1.4113x over previous
//
#include <hip/hip_runtime.h>

#define BN_EPS 1e-5f

typedef __attribute__((ext_vector_type(8))) __bf16 bf16x8;
typedef __attribute__((ext_vector_type(4))) float f32x4;

__device__ __forceinline__ unsigned short f2bf(float f) {
    unsigned int u = __float_as_uint(f);
    u = (u + 0x7fffu + ((u >> 16) & 1u)) >> 16;
    return (unsigned short)u;
}
__device__ __forceinline__ float bfLo(unsigned int w) { return __uint_as_float(w << 16); }
__device__ __forceinline__ float bfHi(unsigned int w) { return __uint_as_float(w & 0xffff0000u); }

__device__ __forceinline__ void accRow(float* acc, uint4 v) {
    acc[0] += bfLo(v.x); acc[1] += bfHi(v.x);
    acc[2] += bfLo(v.y); acc[3] += bfHi(v.y);
    acc[4] += bfLo(v.z); acc[5] += bfHi(v.z);
    acc[6] += bfLo(v.w); acc[7] += bfHi(v.w);
}
__device__ __forceinline__ void accRowBN(float* acc, uint4 v, const float* a8, const float* c8) {
    acc[0] += fmaxf(fmaf(bfLo(v.x), a8[0], c8[0]), 0.f);
    acc[1] += fmaxf(fmaf(bfHi(v.x), a8[1], c8[1]), 0.f);
    acc[2] += fmaxf(fmaf(bfLo(v.y), a8[2], c8[2]), 0.f);
    acc[3] += fmaxf(fmaf(bfHi(v.y), a8[3], c8[3]), 0.f);
    acc[4] += fmaxf(fmaf(bfLo(v.z), a8[4], c8[4]), 0.f);
    acc[5] += fmaxf(fmaf(bfHi(v.z), a8[5], c8[5]), 0.f);
    acc[6] += fmaxf(fmaf(bfLo(v.w), a8[6], c8[6]), 0.f);
    acc[7] += fmaxf(fmaf(bfHi(v.w), a8[7], c8[7]), 0.f);
}

// ===== one-time prep: x->bf16, swizzle 3 weights, AND degree histogram (grid-stride) =====
// Wsw[((ct*4+q)*64 + l)*8 + j] = bf16( W[q*32 + (l>>4)*8 + j][ct*16 + (l&15)] )
__global__ void convert_prep_hist(const float* __restrict__ x, unsigned short* __restrict__ hb,
                                  int total4,
                                  const float* __restrict__ W1, const float* __restrict__ W2,
                                  const float* __restrict__ W3,
                                  unsigned short* __restrict__ w1s, unsigned short* __restrict__ w2s,
                                  unsigned short* __restrict__ w3s,
                                  const int* __restrict__ dst, int* __restrict__ deg, int E) {
    int tid0 = blockIdx.x * blockDim.x + threadIdx.x;
    int stride = gridDim.x * blockDim.x;
    if (tid0 < 40960) {
        int idx = tid0;
        const float* W; unsigned short* O; int NOUT;
        if (idx < 16384)      { W = W1; O = w1s; NOUT = 128; }
        else if (idx < 32768) { W = W2; O = w2s; NOUT = 128; idx -= 16384; }
        else                  { W = W3; O = w3s; NOUT = 64;  idx -= 32768; }
        int j = idx & 7;
        int l = (idx >> 3) & 63;
        int q = (idx >> 9) & 3;
        int ct = idx >> 11;
        int k = q * 32 + ((l >> 4) & 3) * 8 + j;
        int c = ct * 16 + (l & 15);
        O[idx] = f2bf(W[(size_t)k * NOUT + c]);
    }
    for (int i = tid0; i < total4; i += stride) {
        float4 v = reinterpret_cast<const float4*>(x)[i];
        ushort4 o;
        o.x = f2bf(v.x); o.y = f2bf(v.y); o.z = f2bf(v.z); o.w = f2bf(v.w);
        reinterpret_cast<ushort4*>(hb)[i] = o;
    }
    for (int e = tid0; e < E; e += stride) atomicAdd(&deg[dst[e]], 1);
}

// ===== one-kernel CSR: chunk scan -> barrier -> rowptr/pos -> barrier -> fill =====
// grid = nChunks (196 <= co-residency bound), 256 threads.
__global__ void build_csr(const int* __restrict__ deg, int* __restrict__ rowptr,
                          int* __restrict__ pos, int* __restrict__ bsum,
                          int* __restrict__ cnt,
                          const int* __restrict__ src, const int* __restrict__ dst,
                          int* __restrict__ col, int N, int E, int nChunks) {
    __shared__ int s[256];
    const int tid = threadIdx.x;
    const int b = blockIdx.x;
    const int i = b * 256 + tid;
    const int v = (i < N) ? deg[i] : 0;
    s[tid] = v;
    __syncthreads();
#pragma unroll
    for (int off = 1; off < 256; off <<= 1) {
        int t = (tid >= off) ? s[tid - off] : 0;
        __syncthreads();
        s[tid] += t;
        __syncthreads();
    }
    const int incl = s[tid];
    if (tid == 255) bsum[b] = incl;
    __threadfence();
    __syncthreads();
    if (tid == 0) {
        __hip_atomic_fetch_add(&cnt[0], 1, __ATOMIC_ACQ_REL, __HIP_MEMORY_SCOPE_AGENT);
        while (__hip_atomic_load(&cnt[0], __ATOMIC_ACQUIRE, __HIP_MEMORY_SCOPE_AGENT) < nChunks) {}
    }
    __syncthreads();
    // base = sum of chunk totals before b
    int val = (tid < b)
                  ? __hip_atomic_load(&bsum[tid], __ATOMIC_RELAXED, __HIP_MEMORY_SCOPE_AGENT)
                  : 0;
    s[tid] = val;
    __syncthreads();
#pragma unroll
    for (int off = 128; off > 0; off >>= 1) {
        if (tid < off) s[tid] += s[tid + off];
        __syncthreads();
    }
    const int base = s[0];
    if (i < N) {
        int r = incl - v + base;
        rowptr[i] = r;
        pos[i] = r;
    }
    if (b == 0 && tid == 0) rowptr[N] = E;
    __threadfence();
    __syncthreads();
    if (tid == 0) {
        __hip_atomic_fetch_add(&cnt[1], 1, __ATOMIC_ACQ_REL, __HIP_MEMORY_SCOPE_AGENT);
        while (__hip_atomic_load(&cnt[1], __ATOMIC_ACQUIRE, __HIP_MEMORY_SCOPE_AGENT) < nChunks) {}
    }
    __syncthreads();
    // fill CSR columns (grid-stride over edges)
    const int gstride = nChunks * 256;
    for (int e = b * 256 + tid; e < E; e += gstride) {
        int slot = atomicAdd(&pos[dst[e]], 1);
        col[slot] = src[e];
    }
}

// ============ plain gather (layer 1): agg[i] = h[i] + sum_j h[j], 4-edge unroll ============
__global__ void gather_agg_bf(const unsigned short* __restrict__ h,
                              const int* __restrict__ rowptr, const int* __restrict__ col,
                              unsigned short* __restrict__ agg, int N) {
    int t = blockIdx.x * blockDim.x + threadIdx.x;
    int node = t >> 4;
    if (node >= N) return;
    int part = (t & 15) * 8;
    const unsigned short* hp = h + part;
    const int beg = rowptr[node], end = rowptr[node + 1];

    float acc[8];
    {
        uint4 sv = *reinterpret_cast<const uint4*>(hp + (size_t)node * 128);
        acc[0] = bfLo(sv.x); acc[1] = bfHi(sv.x);
        acc[2] = bfLo(sv.y); acc[3] = bfHi(sv.y);
        acc[4] = bfLo(sv.z); acc[5] = bfHi(sv.z);
        acc[6] = bfLo(sv.w); acc[7] = bfHi(sv.w);
    }
    int e = beg;
    for (; e + 3 < end; e += 4) {
        int s0 = col[e], s1 = col[e + 1], s2 = col[e + 2], s3 = col[e + 3];
        uint4 v0 = *reinterpret_cast<const uint4*>(hp + (size_t)s0 * 128);
        uint4 v1 = *reinterpret_cast<const uint4*>(hp + (size_t)s1 * 128);
        uint4 v2 = *reinterpret_cast<const uint4*>(hp + (size_t)s2 * 128);
        uint4 v3 = *reinterpret_cast<const uint4*>(hp + (size_t)s3 * 128);
        accRow(acc, v0); accRow(acc, v1); accRow(acc, v2); accRow(acc, v3);
    }
    for (; e < end; ++e)
        accRow(acc, *reinterpret_cast<const uint4*>(hp + (size_t)col[e] * 128));

    uint4 o;
    o.x = (unsigned int)f2bf(acc[0]) | ((unsigned int)f2bf(acc[1]) << 16);
    o.y = (unsigned int)f2bf(acc[2]) | ((unsigned int)f2bf(acc[3]) << 16);
    o.z = (unsigned int)f2bf(acc[4]) | ((unsigned int)f2bf(acc[5]) << 16);
    o.w = (unsigned int)f2bf(acc[6]) | ((unsigned int)f2bf(acc[7]) << 16);
    *reinterpret_cast<uint4*>(agg + (size_t)node * 128 + part) = o;
}

// ============ BN+ReLU-fused gather (layer 2), 4-edge unroll ============
__global__ void gather_bn_agg(const unsigned short* __restrict__ raw,
                              const float* __restrict__ sumsPad, const float* __restrict__ sqsPad,
                              const float* __restrict__ g, const float* __restrict__ be,
                              const int* __restrict__ rowptr, const int* __restrict__ col,
                              unsigned short* __restrict__ agg, int N, float invN) {
    int t = blockIdx.x * blockDim.x + threadIdx.x;
    int node = t >> 4;
    if (node >= N) return;
    int part = (t & 15) * 8;
    const unsigned short* rp = raw + part;
    float a8[8], c8[8];
#pragma unroll
    for (int k = 0; k < 8; ++k) {
        int c = part + k;
        float m = sumsPad[c * 16] * invN;
        float v = sqsPad[c * 16] * invN - m * m;
        float ai = g[c] * rsqrtf(v + BN_EPS);
        a8[k] = ai;
        c8[k] = be[c] - m * ai;
    }
    const int beg = rowptr[node], end = rowptr[node + 1];
    float acc[8] = {0.f, 0.f, 0.f, 0.f, 0.f, 0.f, 0.f, 0.f};
    accRowBN(acc, *reinterpret_cast<const uint4*>(rp + (size_t)node * 128), a8, c8);  // self
    int e = beg;
    for (; e + 3 < end; e += 4) {
        int s0 = col[e], s1 = col[e + 1], s2 = col[e + 2], s3 = col[e + 3];
        uint4 v0 = *reinterpret_cast<const uint4*>(rp + (size_t)s0 * 128);
        uint4 v1 = *reinterpret_cast<const uint4*>(rp + (size_t)s1 * 128);
        uint4 v2 = *reinterpret_cast<const uint4*>(rp + (size_t)s2 * 128);
        uint4 v3 = *reinterpret_cast<const uint4*>(rp + (size_t)s3 * 128);
        accRowBN(acc, v0, a8, c8); accRowBN(acc, v1, a8, c8);
        accRowBN(acc, v2, a8, c8); accRowBN(acc, v3, a8, c8);
    }
    for (; e < end; ++e)
        accRowBN(acc, *reinterpret_cast<const uint4*>(rp + (size_t)col[e] * 128), a8, c8);

    uint4 o;
    o.x = (unsigned int)f2bf(acc[0]) | ((unsigned int)f2bf(acc[1]) << 16);
    o.y = (unsigned int)f2bf(acc[2]) | ((unsigned int)f2bf(acc[3]) << 16);
    o.z = (unsigned int)f2bf(acc[4]) | ((unsigned int)f2bf(acc[5]) << 16);
    o.w = (unsigned int)f2bf(acc[6]) | ((unsigned int)f2bf(acc[7]) << 16);
    *reinterpret_cast<uint4*>(agg + (size_t)node * 128 + part) = o;
}

// ========== MFMA GEMM (NOUT=128) + bias + fused column stats; bf16 raw out ==========
__global__ __launch_bounds__(256) void gemm128_stats(const unsigned short* __restrict__ A,
                                                     const unsigned short* __restrict__ Wsw,
                                                     const float* __restrict__ bias,
                                                     unsigned short* __restrict__ outb,
                                                     float* __restrict__ sumsPad,
                                                     float* __restrict__ sqsPad, int N) {
    __shared__ float red[2][4][128];
    const int lane = threadIdx.x & 63;
    const int w = threadIdx.x >> 6;
    const int r0 = blockIdx.x * 64 + w * 16;
    int arow = r0 + (lane & 15);
    if (arow >= N) arow = N - 1;
    const int kb = lane >> 4;
    const unsigned short* ap = A + (size_t)arow * 128 + kb * 8;

    bf16x8 a[4];
#pragma unroll
    for (int q = 0; q < 4; ++q) a[q] = *reinterpret_cast<const bf16x8*>(ap + q * 32);

    f32x4 acc[8];
#pragma unroll
    for (int ct = 0; ct < 8; ++ct) acc[ct] = (f32x4){0.f, 0.f, 0.f, 0.f};

    const bf16x8* wp = reinterpret_cast<const bf16x8*>(Wsw) + lane;
#pragma unroll
    for (int ct = 0; ct < 8; ++ct)
#pragma unroll
        for (int q = 0; q < 4; ++q)
            acc[ct] = __builtin_amdgcn_mfma_f32_16x16x32_bf16(a[q], wp[(ct * 4 + q) * 64],
                                                              acc[ct], 0, 0, 0);

    const int crow0 = r0 + (lane >> 4) * 4;
    const int ccol = lane & 15;
#pragma unroll
    for (int ct = 0; ct < 8; ++ct) {
        int c = ct * 16 + ccol;
        float bv = bias[c];
        float s = 0.f, qq = 0.f;
#pragma unroll
        for (int j = 0; j < 4; ++j) {
            int r = crow0 + j;
            if (r < N) {
                float o = acc[ct][j] + bv;
                outb[(size_t)r * 128 + c] = f2bf(o);
                s += o; qq += o * o;
            }
        }
        s += __shfl_xor(s, 16); s += __shfl_xor(s, 32);
        qq += __shfl_xor(qq, 16); qq += __shfl_xor(qq, 32);
        if (lane < 16) { red[0][w][c] = s; red[1][w][c] = qq; }
    }
    __syncthreads();
    int tid = threadIdx.x;
    if (tid < 128) {
        float S = red[0][0][tid] + red[0][1][tid] + red[0][2][tid] + red[0][3][tid];
        atomicAdd(&sumsPad[tid * 16], S);
    } else {
        int c = tid - 128;
        float Q = red[1][0][c] + red[1][1][c] + red[1][2][c] + red[1][3][c];
        atomicAdd(&sqsPad[c * 16], Q);
    }
}

// ========== MFMA GEMM (NOUT=64) with inline BN2+ReLU on A; M = relu(bn(raw)) @ W3 (NO bias) ==========
__global__ __launch_bounds__(256) void gemm64_bn(const unsigned short* __restrict__ raw,
                                                 const float* __restrict__ sumsPad,
                                                 const float* __restrict__ sqsPad,
                                                 const float* __restrict__ g,
                                                 const float* __restrict__ be,
                                                 const unsigned short* __restrict__ Wsw,
                                                 unsigned short* __restrict__ M, int N,
                                                 float invN) {
    const int lane = threadIdx.x & 63;
    const int w = threadIdx.x >> 6;
    const int r0 = blockIdx.x * 64 + w * 16;
    int arow = r0 + (lane & 15);
    if (arow >= N) arow = N - 1;
    const int kb = lane >> 4;
    const unsigned short* ap = raw + (size_t)arow * 128 + kb * 8;

    bf16x8 a[4];
#pragma unroll
    for (int q = 0; q < 4; ++q) {
        uint4 rv = *reinterpret_cast<const uint4*>(ap + q * 32);
        float hh[8] = {bfLo(rv.x), bfHi(rv.x), bfLo(rv.y), bfHi(rv.y),
                       bfLo(rv.z), bfHi(rv.z), bfLo(rv.w), bfHi(rv.w)};
        unsigned int pk[4];
#pragma unroll
        for (int p = 0; p < 4; ++p) {
            unsigned int lohi[2];
#pragma unroll
            for (int hl = 0; hl < 2; ++hl) {
                int j = p * 2 + hl;
                int c = q * 32 + kb * 8 + j;
                float mcol = sumsPad[c * 16] * invN;
                float var = sqsPad[c * 16] * invN - mcol * mcol;
                float ai = g[c] * rsqrtf(var + BN_EPS);
                float ci = be[c] - mcol * ai;
                lohi[hl] = f2bf(fmaxf(fmaf(hh[j], ai, ci), 0.f));
            }
            pk[p] = lohi[0] | (lohi[1] << 16);
        }
        uint4 hp;
        hp.x = pk[0]; hp.y = pk[1]; hp.z = pk[2]; hp.w = pk[3];
        a[q] = *reinterpret_cast<bf16x8*>(&hp);
    }

    f32x4 acc[4];
#pragma unroll
    for (int ct = 0; ct < 4; ++ct) acc[ct] = (f32x4){0.f, 0.f, 0.f, 0.f};

    const bf16x8* wp = reinterpret_cast<const bf16x8*>(Wsw) + lane;
#pragma unroll
    for (int ct = 0; ct < 4; ++ct)
#pragma unroll
        for (int q = 0; q < 4; ++q)
            acc[ct] = __builtin_amdgcn_mfma_f32_16x16x32_bf16(a[q], wp[(ct * 4 + q) * 64],
                                                              acc[ct], 0, 0, 0);

    const int crow0 = r0 + (lane >> 4) * 4;
    const int ccol = lane & 15;
#pragma unroll
    for (int ct = 0; ct < 4; ++ct) {
        int c = ct * 16 + ccol;
#pragma unroll
        for (int j = 0; j < 4; ++j) {
            int r = crow0 + j;
            if (r < N) M[(size_t)r * 64 + c] = f2bf(acc[ct][j]);
        }
    }
}

// ========== layer-3 gather on M (64-wide) + bias + log_softmax; 8 lanes/node ==========
__global__ void gather64_lsm(const unsigned short* __restrict__ M,
                             const int* __restrict__ rowptr, const int* __restrict__ col,
                             const float* __restrict__ bias, float* __restrict__ out, int N) {
    int t = blockIdx.x * blockDim.x + threadIdx.x;
    int node = t >> 3;
    if (node >= N) return;
    int part = (t & 7) * 8;
    const unsigned short* mp = M + part;
    const int beg = rowptr[node], end = rowptr[node + 1];

    float acc[8];
    {
        uint4 sv = *reinterpret_cast<const uint4*>(mp + (size_t)node * 64);
        acc[0] = bfLo(sv.x); acc[1] = bfHi(sv.x);
        acc[2] = bfLo(sv.y); acc[3] = bfHi(sv.y);
        acc[4] = bfLo(sv.z); acc[5] = bfHi(sv.z);
        acc[6] = bfLo(sv.w); acc[7] = bfHi(sv.w);
    }
    int e = beg;
    for (; e + 3 < end; e += 4) {
        int s0 = col[e], s1 = col[e + 1], s2 = col[e + 2], s3 = col[e + 3];
        uint4 v0 = *reinterpret_cast<const uint4*>(mp + (size_t)s0 * 64);
        uint4 v1 = *reinterpret_cast<const uint4*>(mp + (size_t)s1 * 64);
        uint4 v2 = *reinterpret_cast<const uint4*>(mp + (size_t)s2 * 64);
        uint4 v3 = *reinterpret_cast<const uint4*>(mp + (size_t)s3 * 64);
        accRow(acc, v0); accRow(acc, v1); accRow(acc, v2); accRow(acc, v3);
    }
    for (; e < end; ++e)
        accRow(acc, *reinterpret_cast<const uint4*>(mp + (size_t)col[e] * 64));

#pragma unroll
    for (int k = 0; k < 8; ++k) acc[k] += bias[part + k];

    float m = acc[0];
#pragma unroll
    for (int k = 1; k < 8; ++k) m = fmaxf(m, acc[k]);
#pragma unroll
    for (int off = 1; off < 8; off <<= 1) m = fmaxf(m, __shfl_xor(m, off));
    float s = 0.f;
#pragma unroll
    for (int k = 0; k < 8; ++k) s += __expf(acc[k] - m);
#pragma unroll
    for (int off = 1; off < 8; off <<= 1) s += __shfl_xor(s, off);
    float ml = m + __logf(s);

    float4 o0, o1;
    o0.x = acc[0] - ml; o0.y = acc[1] - ml; o0.z = acc[2] - ml; o0.w = acc[3] - ml;
    o1.x = acc[4] - ml; o1.y = acc[5] - ml; o1.z = acc[6] - ml; o1.w = acc[7] - ml;
    float* op = out + (size_t)node * 64 + part;
    *reinterpret_cast<float4*>(op) = o0;
    *reinterpret_cast<float4*>(op + 4) = o1;
}

extern "C" void kernel_launch(void* const* d_in, const int* in_sizes, int n_in,
                              void* d_out, int out_size, void* d_ws, size_t ws_size,
                              hipStream_t stream) {
    const float* x   = (const float*)d_in[0];
    const int*   ei  = (const int*)d_in[1];
    const float* W1  = (const float*)d_in[2];
    const float* b1  = (const float*)d_in[3];
    const float* g1  = (const float*)d_in[4];
    const float* be1 = (const float*)d_in[5];
    const float* W2  = (const float*)d_in[6];
    const float* b2  = (const float*)d_in[7];
    const float* g2  = (const float*)d_in[8];
    const float* be2 = (const float*)d_in[9];
    const float* W3  = (const float*)d_in[10];
    const float* b3  = (const float*)d_in[11];

    const int N = in_sizes[0] / 128;
    const int E = in_sizes[1] / 2;
    const int* src = ei;
    const int* dst = ei + E;

    // ---- workspace carve-up; [statsPad|cnts|deg] is one memset region ----
    float* statsPad = (float*)d_ws;                 // 4 x 2048 (stride-16 cols)
    float* sums1 = statsPad;
    float* sqs1  = statsPad + 2048;
    float* sums2 = statsPad + 4096;
    float* sqs2  = statsPad + 6144;
    int* cnts   = (int*)(statsPad + 8192);          // 64 (grid-barrier counters)
    int* deg    = cnts + 64;                        // N
    int* pos    = deg + N;                          // N
    int* rowptr = pos + N;                          // N+1
    int* bsum   = rowptr + N + 1;                   // 256
    int* colidx = bsum + 256;                       // E
    unsigned short* hb   = (unsigned short*)(colidx + E);   // N*128 bf16 (x)
    unsigned short* rawb = hb + (size_t)N * 128;            // N*128 bf16 (gemm raw out)
    unsigned short* agb  = rawb + (size_t)N * 128;          // N*128 bf16 (agg)
    unsigned short* m3   = agb + (size_t)N * 128;           // N*64 bf16 (layer3 pre-agg)
    unsigned short* w1s  = m3 + (size_t)N * 64;             // 16384
    unsigned short* w2s  = w1s + 16384;                     // 16384
    unsigned short* w3s  = w2s + 16384;                     // 8192

    const int nChunks = (N + 255) / 256;
    const int eBlocks = (E + 255) / 256;
    const int gemmBlocks = (N + 63) / 64;
    const int gatherBlocks = (N * 16 + 255) / 256;
    const int gather64Blocks = (N * 8 + 255) / 256;
    const int total4 = N * 128 / 4;
    const float invN = 1.0f / N;
    (void)eBlocks;

    // ---- one memset: stats + counters + deg ----
    hipMemsetAsync(statsPad, 0, 8192 * sizeof(float) + (64 + (size_t)N) * sizeof(int), stream);

    // ---- prep (x->bf16, W swizzle, degree hist) + CSR build (1 kernel each) ----
    convert_prep_hist<<<2048, 256, 0, stream>>>(x, hb, total4, W1, W2, W3, w1s, w2s, w3s,
                                                dst, deg, E);
    build_csr<<<nChunks, 256, 0, stream>>>(deg, rowptr, pos, bsum, cnts, src, dst, colidx,
                                           N, E, nChunks);

    // ---- layer 1 ----
    gather_agg_bf<<<gatherBlocks, 256, 0, stream>>>(hb, rowptr, colidx, agb, N);
    gemm128_stats<<<gemmBlocks, 256, 0, stream>>>(agb, w1s, b1, rawb, sums1, sqs1, N);

    // ---- layer 2 (BN1+ReLU fused into gather) ----
    gather_bn_agg<<<gatherBlocks, 256, 0, stream>>>(rawb, sums1, sqs1, g1, be1, rowptr, colidx,
                                                    agb, N, invN);
    gemm128_stats<<<gemmBlocks, 256, 0, stream>>>(agb, w2s, b2, rawb, sums2, sqs2, N);

    // ---- layer 3: GEMM first (BN2+ReLU inline), then 64-wide gather + bias + lsm ----
    gemm64_bn<<<gemmBlocks, 256, 0, stream>>>(rawb, sums2, sqs2, g2, be2, w3s, m3, N, invN);
    gather64_lsm<<<gather64Blocks, 256, 0, stream>>>(m3, rowptr, colidx, b3, (float*)d_out, N);
}

// Round 10
// 264.242 us; speedup vs baseline: 1.5078x; 1.0684x over previous
//
#include <hip/hip_runtime.h>

#define BN_EPS 1e-5f

typedef __attribute__((ext_vector_type(8))) __bf16 bf16x8;
typedef __attribute__((ext_vector_type(4))) float f32x4;

__device__ __forceinline__ unsigned short f2bf(float f) {
    unsigned int u = __float_as_uint(f);
    u = (u + 0x7fffu + ((u >> 16) & 1u)) >> 16;
    return (unsigned short)u;
}
__device__ __forceinline__ float bfLo(unsigned int w) { return __uint_as_float(w << 16); }
__device__ __forceinline__ float bfHi(unsigned int w) { return __uint_as_float(w & 0xffff0000u); }

__device__ __forceinline__ void accRow(float* acc, uint4 v) {
    acc[0] += bfLo(v.x); acc[1] += bfHi(v.x);
    acc[2] += bfLo(v.y); acc[3] += bfHi(v.y);
    acc[4] += bfLo(v.z); acc[5] += bfHi(v.z);
    acc[6] += bfLo(v.w); acc[7] += bfHi(v.w);
}
__device__ __forceinline__ void accRowBN(float* acc, uint4 v, const float* a8, const float* c8) {
    acc[0] += fmaxf(fmaf(bfLo(v.x), a8[0], c8[0]), 0.f);
    acc[1] += fmaxf(fmaf(bfHi(v.x), a8[1], c8[1]), 0.f);
    acc[2] += fmaxf(fmaf(bfLo(v.y), a8[2], c8[2]), 0.f);
    acc[3] += fmaxf(fmaf(bfHi(v.y), a8[3], c8[3]), 0.f);
    acc[4] += fmaxf(fmaf(bfLo(v.z), a8[4], c8[4]), 0.f);
    acc[5] += fmaxf(fmaf(bfHi(v.z), a8[5], c8[5]), 0.f);
    acc[6] += fmaxf(fmaf(bfLo(v.w), a8[6], c8[6]), 0.f);
    acc[7] += fmaxf(fmaf(bfHi(v.w), a8[7], c8[7]), 0.f);
}

// ===== one-time prep: x->bf16, swizzle 3 weights, AND degree histogram (grid-stride) =====
// Wsw[((ct*4+q)*64 + l)*8 + j] = bf16( W[q*32 + (l>>4)*8 + j][ct*16 + (l&15)] )
__global__ void convert_prep_hist(const float* __restrict__ x, unsigned short* __restrict__ hb,
                                  int total4,
                                  const float* __restrict__ W1, const float* __restrict__ W2,
                                  const float* __restrict__ W3,
                                  unsigned short* __restrict__ w1s, unsigned short* __restrict__ w2s,
                                  unsigned short* __restrict__ w3s,
                                  const int* __restrict__ dst, int* __restrict__ deg, int E) {
    int tid0 = blockIdx.x * blockDim.x + threadIdx.x;
    int stride = gridDim.x * blockDim.x;
    if (tid0 < 40960) {
        int idx = tid0;
        const float* W; unsigned short* O; int NOUT;
        if (idx < 16384)      { W = W1; O = w1s; NOUT = 128; }
        else if (idx < 32768) { W = W2; O = w2s; NOUT = 128; idx -= 16384; }
        else                  { W = W3; O = w3s; NOUT = 64;  idx -= 32768; }
        int j = idx & 7;
        int l = (idx >> 3) & 63;
        int q = (idx >> 9) & 3;
        int ct = idx >> 11;
        int k = q * 32 + ((l >> 4) & 3) * 8 + j;
        int c = ct * 16 + (l & 15);
        O[idx] = f2bf(W[(size_t)k * NOUT + c]);
    }
    for (int i = tid0; i < total4; i += stride) {
        float4 v = reinterpret_cast<const float4*>(x)[i];
        ushort4 o;
        o.x = f2bf(v.x); o.y = f2bf(v.y); o.z = f2bf(v.z); o.w = f2bf(v.w);
        reinterpret_cast<ushort4*>(hb)[i] = o;
    }
    for (int e = tid0; e < E; e += stride) atomicAdd(&deg[dst[e]], 1);
}

// ===== merged scan: chunk scan -> grid barrier -> top-scan -> rowptr/pos =====
// grid = nChunks (196, co-resident), 256 threads.
__global__ void build_rowptr(const int* __restrict__ deg, int* __restrict__ rowptr,
                             int* __restrict__ pos, int* __restrict__ bsum,
                             int* __restrict__ arrive, int N, int E, int nChunks) {
    __shared__ int s[256];
    const int tid = threadIdx.x;
    const int b = blockIdx.x;
    const int i = b * 256 + tid;
    const int v = (i < N) ? deg[i] : 0;
    s[tid] = v;
    __syncthreads();
#pragma unroll
    for (int off = 1; off < 256; off <<= 1) {
        int t = (tid >= off) ? s[tid - off] : 0;
        __syncthreads();
        s[tid] += t;
        __syncthreads();
    }
    const int incl = s[tid];
    if (tid == 255) bsum[b] = incl;
    __threadfence();
    __syncthreads();
    if (tid == 0) {
        __hip_atomic_fetch_add(arrive, 1, __ATOMIC_ACQ_REL, __HIP_MEMORY_SCOPE_AGENT);
        while (__hip_atomic_load(arrive, __ATOMIC_ACQUIRE, __HIP_MEMORY_SCOPE_AGENT) < nChunks) {}
    }
    __syncthreads();
    // base = sum of chunk totals before b
    int val = (tid < b)
                  ? __hip_atomic_load(&bsum[tid], __ATOMIC_RELAXED, __HIP_MEMORY_SCOPE_AGENT)
                  : 0;
    s[tid] = val;
    __syncthreads();
#pragma unroll
    for (int off = 128; off > 0; off >>= 1) {
        if (tid < off) s[tid] += s[tid + off];
        __syncthreads();
    }
    const int base = s[0];
    if (i < N) {
        int r = incl - v + base;
        rowptr[i] = r;
        pos[i] = r;
    }
    if (b == 0 && tid == 0) rowptr[N] = E;
}

// ===== CSR fill: one thread per edge (max TLP for the dependent atomic+scatter) =====
__global__ void fill_kernel(const int* __restrict__ src, const int* __restrict__ dst,
                            int* __restrict__ pos, int* __restrict__ col, int E) {
    int e = blockIdx.x * blockDim.x + threadIdx.x;
    if (e < E) {
        int slot = atomicAdd(&pos[dst[e]], 1);
        col[slot] = src[e];
    }
}

// ============ plain gather (layer 1): agg[i] = h[i] + sum_j h[j], 4-edge unroll ============
__global__ void gather_agg_bf(const unsigned short* __restrict__ h,
                              const int* __restrict__ rowptr, const int* __restrict__ col,
                              unsigned short* __restrict__ agg, int N) {
    int t = blockIdx.x * blockDim.x + threadIdx.x;
    int node = t >> 4;
    if (node >= N) return;
    int part = (t & 15) * 8;
    const unsigned short* hp = h + part;
    const int beg = rowptr[node], end = rowptr[node + 1];

    float acc[8];
    {
        uint4 sv = *reinterpret_cast<const uint4*>(hp + (size_t)node * 128);
        acc[0] = bfLo(sv.x); acc[1] = bfHi(sv.x);
        acc[2] = bfLo(sv.y); acc[3] = bfHi(sv.y);
        acc[4] = bfLo(sv.z); acc[5] = bfHi(sv.z);
        acc[6] = bfLo(sv.w); acc[7] = bfHi(sv.w);
    }
    int e = beg;
    for (; e + 3 < end; e += 4) {
        int s0 = col[e], s1 = col[e + 1], s2 = col[e + 2], s3 = col[e + 3];
        uint4 v0 = *reinterpret_cast<const uint4*>(hp + (size_t)s0 * 128);
        uint4 v1 = *reinterpret_cast<const uint4*>(hp + (size_t)s1 * 128);
        uint4 v2 = *reinterpret_cast<const uint4*>(hp + (size_t)s2 * 128);
        uint4 v3 = *reinterpret_cast<const uint4*>(hp + (size_t)s3 * 128);
        accRow(acc, v0); accRow(acc, v1); accRow(acc, v2); accRow(acc, v3);
    }
    for (; e < end; ++e)
        accRow(acc, *reinterpret_cast<const uint4*>(hp + (size_t)col[e] * 128));

    uint4 o;
    o.x = (unsigned int)f2bf(acc[0]) | ((unsigned int)f2bf(acc[1]) << 16);
    o.y = (unsigned int)f2bf(acc[2]) | ((unsigned int)f2bf(acc[3]) << 16);
    o.z = (unsigned int)f2bf(acc[4]) | ((unsigned int)f2bf(acc[5]) << 16);
    o.w = (unsigned int)f2bf(acc[6]) | ((unsigned int)f2bf(acc[7]) << 16);
    *reinterpret_cast<uint4*>(agg + (size_t)node * 128 + part) = o;
}

// ============ BN+ReLU-fused gather (layer 2), 4-edge unroll ============
__global__ void gather_bn_agg(const unsigned short* __restrict__ raw,
                              const float* __restrict__ sumsPad, const float* __restrict__ sqsPad,
                              const float* __restrict__ g, const float* __restrict__ be,
                              const int* __restrict__ rowptr, const int* __restrict__ col,
                              unsigned short* __restrict__ agg, int N, float invN) {
    int t = blockIdx.x * blockDim.x + threadIdx.x;
    int node = t >> 4;
    if (node >= N) return;
    int part = (t & 15) * 8;
    const unsigned short* rp = raw + part;
    float a8[8], c8[8];
#pragma unroll
    for (int k = 0; k < 8; ++k) {
        int c = part + k;
        float m = sumsPad[c * 16] * invN;
        float v = sqsPad[c * 16] * invN - m * m;
        float ai = g[c] * rsqrtf(v + BN_EPS);
        a8[k] = ai;
        c8[k] = be[c] - m * ai;
    }
    const int beg = rowptr[node], end = rowptr[node + 1];
    float acc[8] = {0.f, 0.f, 0.f, 0.f, 0.f, 0.f, 0.f, 0.f};
    accRowBN(acc, *reinterpret_cast<const uint4*>(rp + (size_t)node * 128), a8, c8);  // self
    int e = beg;
    for (; e + 3 < end; e += 4) {
        int s0 = col[e], s1 = col[e + 1], s2 = col[e + 2], s3 = col[e + 3];
        uint4 v0 = *reinterpret_cast<const uint4*>(rp + (size_t)s0 * 128);
        uint4 v1 = *reinterpret_cast<const uint4*>(rp + (size_t)s1 * 128);
        uint4 v2 = *reinterpret_cast<const uint4*>(rp + (size_t)s2 * 128);
        uint4 v3 = *reinterpret_cast<const uint4*>(rp + (size_t)s3 * 128);
        accRowBN(acc, v0, a8, c8); accRowBN(acc, v1, a8, c8);
        accRowBN(acc, v2, a8, c8); accRowBN(acc, v3, a8, c8);
    }
    for (; e < end; ++e)
        accRowBN(acc, *reinterpret_cast<const uint4*>(rp + (size_t)col[e] * 128), a8, c8);

    uint4 o;
    o.x = (unsigned int)f2bf(acc[0]) | ((unsigned int)f2bf(acc[1]) << 16);
    o.y = (unsigned int)f2bf(acc[2]) | ((unsigned int)f2bf(acc[3]) << 16);
    o.z = (unsigned int)f2bf(acc[4]) | ((unsigned int)f2bf(acc[5]) << 16);
    o.w = (unsigned int)f2bf(acc[6]) | ((unsigned int)f2bf(acc[7]) << 16);
    *reinterpret_cast<uint4*>(agg + (size_t)node * 128 + part) = o;
}

// ========== MFMA GEMM (NOUT=128) + bias + fused column stats; bf16 raw out ==========
__global__ __launch_bounds__(256) void gemm128_stats(const unsigned short* __restrict__ A,
                                                     const unsigned short* __restrict__ Wsw,
                                                     const float* __restrict__ bias,
                                                     unsigned short* __restrict__ outb,
                                                     float* __restrict__ sumsPad,
                                                     float* __restrict__ sqsPad, int N) {
    __shared__ float red[2][4][128];
    const int lane = threadIdx.x & 63;
    const int w = threadIdx.x >> 6;
    const int r0 = blockIdx.x * 64 + w * 16;
    int arow = r0 + (lane & 15);
    if (arow >= N) arow = N - 1;
    const int kb = lane >> 4;
    const unsigned short* ap = A + (size_t)arow * 128 + kb * 8;

    bf16x8 a[4];
#pragma unroll
    for (int q = 0; q < 4; ++q) a[q] = *reinterpret_cast<const bf16x8*>(ap + q * 32);

    f32x4 acc[8];
#pragma unroll
    for (int ct = 0; ct < 8; ++ct) acc[ct] = (f32x4){0.f, 0.f, 0.f, 0.f};

    const bf16x8* wp = reinterpret_cast<const bf16x8*>(Wsw) + lane;
#pragma unroll
    for (int ct = 0; ct < 8; ++ct)
#pragma unroll
        for (int q = 0; q < 4; ++q)
            acc[ct] = __builtin_amdgcn_mfma_f32_16x16x32_bf16(a[q], wp[(ct * 4 + q) * 64],
                                                              acc[ct], 0, 0, 0);

    const int crow0 = r0 + (lane >> 4) * 4;
    const int ccol = lane & 15;
#pragma unroll
    for (int ct = 0; ct < 8; ++ct) {
        int c = ct * 16 + ccol;
        float bv = bias[c];
        float s = 0.f, qq = 0.f;
#pragma unroll
        for (int j = 0; j < 4; ++j) {
            int r = crow0 + j;
            if (r < N) {
                float o = acc[ct][j] + bv;
                outb[(size_t)r * 128 + c] = f2bf(o);
                s += o; qq += o * o;
            }
        }
        s += __shfl_xor(s, 16); s += __shfl_xor(s, 32);
        qq += __shfl_xor(qq, 16); qq += __shfl_xor(qq, 32);
        if (lane < 16) { red[0][w][c] = s; red[1][w][c] = qq; }
    }
    __syncthreads();
    int tid = threadIdx.x;
    if (tid < 128) {
        float S = red[0][0][tid] + red[0][1][tid] + red[0][2][tid] + red[0][3][tid];
        atomicAdd(&sumsPad[tid * 16], S);
    } else {
        int c = tid - 128;
        float Q = red[1][0][c] + red[1][1][c] + red[1][2][c] + red[1][3][c];
        atomicAdd(&sqsPad[c * 16], Q);
    }
}

// ========== MFMA GEMM (NOUT=64) with inline BN2+ReLU on A; M = relu(bn(raw)) @ W3 (NO bias) ==========
__global__ __launch_bounds__(256) void gemm64_bn(const unsigned short* __restrict__ raw,
                                                 const float* __restrict__ sumsPad,
                                                 const float* __restrict__ sqsPad,
                                                 const float* __restrict__ g,
                                                 const float* __restrict__ be,
                                                 const unsigned short* __restrict__ Wsw,
                                                 unsigned short* __restrict__ M, int N,
                                                 float invN) {
    const int lane = threadIdx.x & 63;
    const int w = threadIdx.x >> 6;
    const int r0 = blockIdx.x * 64 + w * 16;
    int arow = r0 + (lane & 15);
    if (arow >= N) arow = N - 1;
    const int kb = lane >> 4;
    const unsigned short* ap = raw + (size_t)arow * 128 + kb * 8;

    bf16x8 a[4];
#pragma unroll
    for (int q = 0; q < 4; ++q) {
        uint4 rv = *reinterpret_cast<const uint4*>(ap + q * 32);
        float hh[8] = {bfLo(rv.x), bfHi(rv.x), bfLo(rv.y), bfHi(rv.y),
                       bfLo(rv.z), bfHi(rv.z), bfLo(rv.w), bfHi(rv.w)};
        unsigned int pk[4];
#pragma unroll
        for (int p = 0; p < 4; ++p) {
            unsigned int lohi[2];
#pragma unroll
            for (int hl = 0; hl < 2; ++hl) {
                int j = p * 2 + hl;
                int c = q * 32 + kb * 8 + j;
                float mcol = sumsPad[c * 16] * invN;
                float var = sqsPad[c * 16] * invN - mcol * mcol;
                float ai = g[c] * rsqrtf(var + BN_EPS);
                float ci = be[c] - mcol * ai;
                lohi[hl] = f2bf(fmaxf(fmaf(hh[j], ai, ci), 0.f));
            }
            pk[p] = lohi[0] | (lohi[1] << 16);
        }
        uint4 hp;
        hp.x = pk[0]; hp.y = pk[1]; hp.z = pk[2]; hp.w = pk[3];
        a[q] = *reinterpret_cast<bf16x8*>(&hp);
    }

    f32x4 acc[4];
#pragma unroll
    for (int ct = 0; ct < 4; ++ct) acc[ct] = (f32x4){0.f, 0.f, 0.f, 0.f};

    const bf16x8* wp = reinterpret_cast<const bf16x8*>(Wsw) + lane;
#pragma unroll
    for (int ct = 0; ct < 4; ++ct)
#pragma unroll
        for (int q = 0; q < 4; ++q)
            acc[ct] = __builtin_amdgcn_mfma_f32_16x16x32_bf16(a[q], wp[(ct * 4 + q) * 64],
                                                              acc[ct], 0, 0, 0);

    const int crow0 = r0 + (lane >> 4) * 4;
    const int ccol = lane & 15;
#pragma unroll
    for (int ct = 0; ct < 4; ++ct) {
        int c = ct * 16 + ccol;
#pragma unroll
        for (int j = 0; j < 4; ++j) {
            int r = crow0 + j;
            if (r < N) M[(size_t)r * 64 + c] = f2bf(acc[ct][j]);
        }
    }
}

// ========== layer-3 gather on M (64-wide) + bias + log_softmax; 8 lanes/node ==========
__global__ void gather64_lsm(const unsigned short* __restrict__ M,
                             const int* __restrict__ rowptr, const int* __restrict__ col,
                             const float* __restrict__ bias, float* __restrict__ out, int N) {
    int t = blockIdx.x * blockDim.x + threadIdx.x;
    int node = t >> 3;
    if (node >= N) return;
    int part = (t & 7) * 8;
    const unsigned short* mp = M + part;
    const int beg = rowptr[node], end = rowptr[node + 1];

    float acc[8];
    {
        uint4 sv = *reinterpret_cast<const uint4*>(mp + (size_t)node * 64);
        acc[0] = bfLo(sv.x); acc[1] = bfHi(sv.x);
        acc[2] = bfLo(sv.y); acc[3] = bfHi(sv.y);
        acc[4] = bfLo(sv.z); acc[5] = bfHi(sv.z);
        acc[6] = bfLo(sv.w); acc[7] = bfHi(sv.w);
    }
    int e = beg;
    for (; e + 3 < end; e += 4) {
        int s0 = col[e], s1 = col[e + 1], s2 = col[e + 2], s3 = col[e + 3];
        uint4 v0 = *reinterpret_cast<const uint4*>(mp + (size_t)s0 * 64);
        uint4 v1 = *reinterpret_cast<const uint4*>(mp + (size_t)s1 * 64);
        uint4 v2 = *reinterpret_cast<const uint4*>(mp + (size_t)s2 * 64);
        uint4 v3 = *reinterpret_cast<const uint4*>(mp + (size_t)s3 * 64);
        accRow(acc, v0); accRow(acc, v1); accRow(acc, v2); accRow(acc, v3);
    }
    for (; e < end; ++e)
        accRow(acc, *reinterpret_cast<const uint4*>(mp + (size_t)col[e] * 64));

#pragma unroll
    for (int k = 0; k < 8; ++k) acc[k] += bias[part + k];

    float m = acc[0];
#pragma unroll
    for (int k = 1; k < 8; ++k) m = fmaxf(m, acc[k]);
#pragma unroll
    for (int off = 1; off < 8; off <<= 1) m = fmaxf(m, __shfl_xor(m, off));
    float s = 0.f;
#pragma unroll
    for (int k = 0; k < 8; ++k) s += __expf(acc[k] - m);
#pragma unroll
    for (int off = 1; off < 8; off <<= 1) s += __shfl_xor(s, off);
    float ml = m + __logf(s);

    float4 o0, o1;
    o0.x = acc[0] - ml; o0.y = acc[1] - ml; o0.z = acc[2] - ml; o0.w = acc[3] - ml;
    o1.x = acc[4] - ml; o1.y = acc[5] - ml; o1.z = acc[6] - ml; o1.w = acc[7] - ml;
    float* op = out + (size_t)node * 64 + part;
    *reinterpret_cast<float4*>(op) = o0;
    *reinterpret_cast<float4*>(op + 4) = o1;
}

extern "C" void kernel_launch(void* const* d_in, const int* in_sizes, int n_in,
                              void* d_out, int out_size, void* d_ws, size_t ws_size,
                              hipStream_t stream) {
    const float* x   = (const float*)d_in[0];
    const int*   ei  = (const int*)d_in[1];
    const float* W1  = (const float*)d_in[2];
    const float* b1  = (const float*)d_in[3];
    const float* g1  = (const float*)d_in[4];
    const float* be1 = (const float*)d_in[5];
    const float* W2  = (const float*)d_in[6];
    const float* b2  = (const float*)d_in[7];
    const float* g2  = (const float*)d_in[8];
    const float* be2 = (const float*)d_in[9];
    const float* W3  = (const float*)d_in[10];
    const float* b3  = (const float*)d_in[11];

    const int N = in_sizes[0] / 128;
    const int E = in_sizes[1] / 2;
    const int* src = ei;
    const int* dst = ei + E;

    // ---- workspace carve-up; [statsPad|cnts|deg] is one memset region ----
    float* statsPad = (float*)d_ws;                 // 4 x 2048 (stride-16 cols)
    float* sums1 = statsPad;
    float* sqs1  = statsPad + 2048;
    float* sums2 = statsPad + 4096;
    float* sqs2  = statsPad + 6144;
    int* cnts   = (int*)(statsPad + 8192);          // 64 (grid-barrier counters)
    int* deg    = cnts + 64;                        // N
    int* pos    = deg + N;                          // N
    int* rowptr = pos + N;                          // N+1
    int* bsum   = rowptr + N + 1;                   // 256
    int* colidx = bsum + 256;                       // E
    unsigned short* hb   = (unsigned short*)(colidx + E);   // N*128 bf16 (x)
    unsigned short* rawb = hb + (size_t)N * 128;            // N*128 bf16 (gemm raw out)
    unsigned short* agb  = rawb + (size_t)N * 128;          // N*128 bf16 (agg)
    unsigned short* m3   = agb + (size_t)N * 128;           // N*64 bf16 (layer3 pre-agg)
    unsigned short* w1s  = m3 + (size_t)N * 64;             // 16384
    unsigned short* w2s  = w1s + 16384;                     // 16384
    unsigned short* w3s  = w2s + 16384;                     // 8192

    const int nChunks = (N + 255) / 256;
    const int eBlocks = (E + 255) / 256;
    const int gemmBlocks = (N + 63) / 64;
    const int gatherBlocks = (N * 16 + 255) / 256;
    const int gather64Blocks = (N * 8 + 255) / 256;
    const int total4 = N * 128 / 4;
    const float invN = 1.0f / N;

    // ---- one memset: stats + counters + deg ----
    hipMemsetAsync(statsPad, 0, 8192 * sizeof(float) + (64 + (size_t)N) * sizeof(int), stream);

    // ---- prep (x->bf16, W swizzle, degree hist); merged scan; wide fill ----
    convert_prep_hist<<<2048, 256, 0, stream>>>(x, hb, total4, W1, W2, W3, w1s, w2s, w3s,
                                                dst, deg, E);
    build_rowptr<<<nChunks, 256, 0, stream>>>(deg, rowptr, pos, bsum, cnts, N, E, nChunks);
    fill_kernel<<<eBlocks, 256, 0, stream>>>(src, dst, pos, colidx, E);

    // ---- layer 1 ----
    gather_agg_bf<<<gatherBlocks, 256, 0, stream>>>(hb, rowptr, colidx, agb, N);
    gemm128_stats<<<gemmBlocks, 256, 0, stream>>>(agb, w1s, b1, rawb, sums1, sqs1, N);

    // ---- layer 2 (BN1+ReLU fused into gather) ----
    gather_bn_agg<<<gatherBlocks, 256, 0, stream>>>(rawb, sums1, sqs1, g1, be1, rowptr, colidx,
                                                    agb, N, invN);
    gemm128_stats<<<gemmBlocks, 256, 0, stream>>>(agb, w2s, b2, rawb, sums2, sqs2, N);

    // ---- layer 3: GEMM first (BN2+ReLU inline), then 64-wide gather + bias + lsm ----
    gemm64_bn<<<gemmBlocks, 256, 0, stream>>>(rawb, sums2, sqs2, g2, be2, w3s, m3, N, invN);
    gather64_lsm<<<gather64Blocks, 256, 0, stream>>>(m3, rowptr, colidx, b3, (float*)d_out, N);
}